// Round 8
// baseline (25.135 us; speedup 1.0000x reference)
//
#include <hip/hip_runtime.h>
#include <math.h>

// SphericalBessel, closed form + zero-fill tail, software-pipelined 2 tiles/block.
// x >= X_l: j_l = s*S_l(z) + c*C_l(z), z=1/x^2 (S2PI pre-folded into coeffs).
// x <  X_l: 0 (|j_l| <= ~5e-4 there).
// Pipeline: flush(tile0) issues global stores WITHOUT vmcnt drain (raw s_barrier +
// lgkmcnt-only wait), so HBM drain overlaps compute(tile1). __syncthreads would
// emit vmcnt(0) and serialize store/compute phases (observed: dur ~= store + compute).

static constexpr int KMODES  = 100;
static constexpr int NTILE   = 64;
static constexpr int LSTRIDE = 101;   // odd stride -> conflict-free ds_write rows
static constexpr int TPB     = 2;     // tiles per block
static constexpr float S2PI  = 0.79788456080286536f; // sqrt(2/pi)

__device__ __forceinline__ float rcpf(float x) { return __builtin_amdgcn_rcpf(x); }

// closed-form polys in z = 1/x^2 (highest degree first), PRE-SCALED by S2PI:
// odd  L: j*S2PI = s*z*sg(z) + c*u*gm(z);  even L: j*S2PI = s*u*sg(z) + c*z*gm(z)
template<int L> struct CFc;
template<> struct CFc<2>{ static constexpr float sg[2]={S2PI*3.f,S2PI*-1.f};                         static constexpr float gm[1]={S2PI*-3.f}; };
template<> struct CFc<3>{ static constexpr float sg[2]={S2PI*15.f,S2PI*-6.f};                        static constexpr float gm[2]={S2PI*-15.f,S2PI*1.f}; };
template<> struct CFc<4>{ static constexpr float sg[3]={S2PI*105.f,S2PI*-45.f,S2PI*1.f};             static constexpr float gm[2]={S2PI*-105.f,S2PI*10.f}; };
template<> struct CFc<5>{ static constexpr float sg[3]={S2PI*945.f,S2PI*-420.f,S2PI*15.f};           static constexpr float gm[3]={S2PI*-945.f,S2PI*105.f,S2PI*-1.f}; };
template<> struct CFc<6>{ static constexpr float sg[4]={S2PI*10395.f,S2PI*-4725.f,S2PI*210.f,S2PI*-1.f};
                          static constexpr float gm[3]={S2PI*-10395.f,S2PI*1260.f,S2PI*-21.f}; };
template<> struct CFc<7>{ static constexpr float sg[4]={S2PI*135135.f,S2PI*-62370.f,S2PI*3150.f,S2PI*-28.f};
                          static constexpr float gm[4]={S2PI*-135135.f,S2PI*17325.f,S2PI*-378.f,S2PI*1.f}; };
template<> struct CFc<8>{ static constexpr float sg[5]={S2PI*2027025.f,S2PI*-945945.f,S2PI*51975.f,S2PI*-630.f,S2PI*1.f};
                          static constexpr float gm[4]={S2PI*-2027025.f,S2PI*270270.f,S2PI*-6930.f,S2PI*36.f}; };
template<> struct CFc<9>{ static constexpr float sg[5]={S2PI*34459425.f,S2PI*-16216200.f,S2PI*945945.f,S2PI*-13860.f,S2PI*45.f};
                          static constexpr float gm[5]={S2PI*-34459425.f,S2PI*4729725.f,S2PI*-135135.f,S2PI*990.f,S2PI*-1.f}; };

// zero-fill cutoffs (literals folded into v_cmp)
template<int L> __device__ __forceinline__ constexpr float xcut() {
  constexpr float t[10] = {0.f,0.f,0.088f,0.29f,0.61f,1.01f,1.48f,2.00f,2.55f,3.14f};
  return t[L];
}

template<int N>
__device__ __forceinline__ float polyH(float z, const float (&a)[N]) {
  float h = a[0];
#pragma unroll
  for (int i = 1; i < N; ++i) h = fmaf(h, z, a[i]);
  return h;
}

template<int L>
__device__ __forceinline__ void do_l(float rv, const float* __restrict__ kvec,
                                     float* ldsrow) {
#pragma unroll
  for (int m = 0; m < 2 * L + 1; ++m) {
    const int KK = L * L + m;
    float kv = kvec[KK];                 // uniform -> s_load
    float x  = rv * kv;
    float res;
    if constexpr (L == 0) {
      res = (__sinf(x) * rcpf(x)) * S2PI;
    } else {
      float s = __sinf(x), c = __cosf(x);   // shared v_mul CSE'd, 2 trans
      float u = rcpf(x);
      float z = u * u;
      if constexpr (L == 1) {
        res = fmaf(s, z, -(c * u)) * S2PI;
      } else {
        float sv = polyH(z, CFc<L>::sg);    // S2PI pre-folded
        float gv = polyH(z, CFc<L>::gm);
        if constexpr (L & 1) res = fmaf(s * z, sv, (c * u) * gv);
        else                 res = fmaf(s * u, sv, (c * z) * gv);
        res = (x < xcut<L>()) ? 0.0f : res;
      }
    }
    ldsrow[KK] = res * kv;               // single v_mul (SGPR kv)
  }
}

__global__ __launch_bounds__(256) void sbf_kernel(const float* __restrict__ r,
                                                  const float* __restrict__ kvec,
                                                  float* __restrict__ out) {
  __shared__ float lds[NTILE * LSTRIDE];   // 25.86 KB -> 6 blocks/CU
  const int tid = threadIdx.x;
  const int w = tid >> 6, lane = tid & 63;
  float* ldsrow = &lds[lane * LSTRIDE];

  // prefetch both tiles' r up front (r is 1 MB, L2-resident)
  float rva[TPB];
#pragma unroll
  for (int t = 0; t < TPB; ++t)
    rva[t] = r[(blockIdx.x + t * gridDim.x) * NTILE + lane];

#pragma unroll
  for (int t = 0; t < TPB; ++t) {
    const int tile = blockIdx.x + t * (int)gridDim.x;
    const float rv = rva[t];
    if (t > 0) {
      // prior flush's ds_reads retired; stores stay in flight (NO vmcnt wait)
      asm volatile("s_waitcnt lgkmcnt(0)" ::: "memory");
      __builtin_amdgcn_s_barrier();
    }
    // cost-balanced partition
    if (w == 0)      { do_l<9>(rv, kvec, ldsrow); do_l<2>(rv, kvec, ldsrow); }
    else if (w == 1) { do_l<8>(rv, kvec, ldsrow); do_l<3>(rv, kvec, ldsrow); }
    else if (w == 2) { do_l<7>(rv, kvec, ldsrow); do_l<4>(rv, kvec, ldsrow); do_l<0>(rv, kvec, ldsrow); }
    else             { do_l<6>(rv, kvec, ldsrow); do_l<5>(rv, kvec, ldsrow); do_l<1>(rv, kvec, ldsrow); }
    // ds_writes visible to all waves; again no vmcnt drain
    asm volatile("s_waitcnt lgkmcnt(0)" ::: "memory");
    __builtin_amdgcn_s_barrier();
    // flush: padded-row gather (b32 reads), coalesced float4 global store, fire-and-forget
    size_t base = (size_t)tile * (size_t)(NTILE * KMODES);
#pragma unroll
    for (int it = 0; it < 7; ++it) {
      int e = it * 1024 + tid * 4;
      if (e < NTILE * KMODES) {
        int row = (int)((unsigned)e / 100u);
        int col = e - row * 100;
        int a = row * LSTRIDE + col;
        float4 v = make_float4(lds[a], lds[a + 1], lds[a + 2], lds[a + 3]);
        *reinterpret_cast<float4*>(&out[base + e]) = v;
      }
    }
  }
}

extern "C" void kernel_launch(void* const* d_in, const int* in_sizes, int n_in,
                              void* d_out, int out_size, void* d_ws, size_t ws_size,
                              hipStream_t stream) {
  const float* r = (const float*)d_in[0];
  const float* k = (const float*)d_in[1];
  float* out = (float*)d_out;
  int N = in_sizes[0];                   // 262144
  int blocks = N / NTILE / TPB;          // 2048
  sbf_kernel<<<blocks, 256, 0, stream>>>(r, k, out);
}

// Round 9
// 24.485 us; speedup vs baseline: 1.0265x; 1.0265x over previous
//
#include <hip/hip_runtime.h>
#include <math.h>

// SphericalBessel, closed form + zero-fill tail.
// x >= X_l: j_l = s*S_l(z) + c*C_l(z), z=1/x^2 (S2PI pre-folded into coeffs).
// x <  X_l: 0 (|j_l| <= ~5e-4 there; X_l balances f32 cancellation vs magnitude).
// LDS staging: LSTRIDE=102 rows. Writes 4-way (1.58x, ok); flush reads are two
// 8B float2 loads per quad (even col, even stride) -> near-conflict-free, vs the
// R7 layout's 28x ds_read_b32 at 8-way (the hidden LDS-pipe bottleneck).
// Flush global stores contiguous per wave (full-line coalescing preserved).

static constexpr int KMODES  = 100;
static constexpr int NTILE   = 64;
static constexpr int LSTRIDE = 102;   // even: 8B-aligned quads; 102%32=6 -> 4-way writes
static constexpr float S2PI  = 0.79788456080286536f; // sqrt(2/pi)

__device__ __forceinline__ float rcpf(float x) { return __builtin_amdgcn_rcpf(x); }

// closed-form polys in z = 1/x^2 (highest degree first), PRE-SCALED by S2PI:
// odd  L: j*S2PI = s*z*sg(z) + c*u*gm(z);  even L: j*S2PI = s*u*sg(z) + c*z*gm(z)
template<int L> struct CFc;
template<> struct CFc<2>{ static constexpr float sg[2]={S2PI*3.f,S2PI*-1.f};                         static constexpr float gm[1]={S2PI*-3.f}; };
template<> struct CFc<3>{ static constexpr float sg[2]={S2PI*15.f,S2PI*-6.f};                        static constexpr float gm[2]={S2PI*-15.f,S2PI*1.f}; };
template<> struct CFc<4>{ static constexpr float sg[3]={S2PI*105.f,S2PI*-45.f,S2PI*1.f};             static constexpr float gm[2]={S2PI*-105.f,S2PI*10.f}; };
template<> struct CFc<5>{ static constexpr float sg[3]={S2PI*945.f,S2PI*-420.f,S2PI*15.f};           static constexpr float gm[3]={S2PI*-945.f,S2PI*105.f,S2PI*-1.f}; };
template<> struct CFc<6>{ static constexpr float sg[4]={S2PI*10395.f,S2PI*-4725.f,S2PI*210.f,S2PI*-1.f};
                          static constexpr float gm[3]={S2PI*-10395.f,S2PI*1260.f,S2PI*-21.f}; };
template<> struct CFc<7>{ static constexpr float sg[4]={S2PI*135135.f,S2PI*-62370.f,S2PI*3150.f,S2PI*-28.f};
                          static constexpr float gm[4]={S2PI*-135135.f,S2PI*17325.f,S2PI*-378.f,S2PI*1.f}; };
template<> struct CFc<8>{ static constexpr float sg[5]={S2PI*2027025.f,S2PI*-945945.f,S2PI*51975.f,S2PI*-630.f,S2PI*1.f};
                          static constexpr float gm[4]={S2PI*-2027025.f,S2PI*270270.f,S2PI*-6930.f,S2PI*36.f}; };
template<> struct CFc<9>{ static constexpr float sg[5]={S2PI*34459425.f,S2PI*-16216200.f,S2PI*945945.f,S2PI*-13860.f,S2PI*45.f};
                          static constexpr float gm[5]={S2PI*-34459425.f,S2PI*4729725.f,S2PI*-135135.f,S2PI*990.f,S2PI*-1.f}; };

template<int L> __device__ __forceinline__ constexpr float xcut() {
  constexpr float t[10] = {0.f,0.f,0.088f,0.29f,0.61f,1.01f,1.48f,2.00f,2.55f,3.14f};
  return t[L];
}

template<int N>
__device__ __forceinline__ float polyH(float z, const float (&a)[N]) {
  float h = a[0];
#pragma unroll
  for (int i = 1; i < N; ++i) h = fmaf(h, z, a[i]);
  return h;
}

template<int L>
__device__ __forceinline__ void do_l(float rv, const float* __restrict__ kvec,
                                     float* ldsrow) {
#pragma unroll
  for (int m = 0; m < 2 * L + 1; ++m) {
    const int KK = L * L + m;
    float kv = kvec[KK];                 // uniform -> s_load
    float x  = rv * kv;
    float res;
    if constexpr (L == 0) {
      res = (__sinf(x) * rcpf(x)) * S2PI;
    } else {
      float s = __sinf(x), c = __cosf(x);  // shared range-scale mul CSE'd
      float u = rcpf(x);
      float z = u * u;
      if constexpr (L == 1) {
        res = fmaf(s, z, -(c * u)) * S2PI;
      } else {
        float sv = polyH(z, CFc<L>::sg);   // S2PI pre-folded
        float gv = polyH(z, CFc<L>::gm);
        if constexpr (L & 1) res = fmaf(s * z, sv, (c * u) * gv);
        else                 res = fmaf(s * u, sv, (c * z) * gv);
        res = (x < xcut<L>()) ? 0.0f : res;
      }
    }
    ldsrow[KK] = res * kv;               // single v_mul (SGPR kv), imm-offset ds_write
  }
}

__global__ __launch_bounds__(256) void sbf_kernel(const float* __restrict__ r,
                                                  const float* __restrict__ kvec,
                                                  float* __restrict__ out) {
  __shared__ float lds[NTILE * LSTRIDE];   // 26.1 KB -> 6 blocks/CU
  const int tid = threadIdx.x;
  const int w = tid >> 6, lane = tid & 63;
  const int n0 = blockIdx.x * NTILE;
  float rv = r[n0 + lane];
  float* ldsrow = &lds[lane * LSTRIDE];
  // cost-balanced l-partition (VALU model: 440/414/402/410)
  if (w == 0)      { do_l<9>(rv, kvec, ldsrow); do_l<2>(rv, kvec, ldsrow); }
  else if (w == 1) { do_l<8>(rv, kvec, ldsrow); do_l<3>(rv, kvec, ldsrow); }
  else if (w == 2) { do_l<7>(rv, kvec, ldsrow); do_l<4>(rv, kvec, ldsrow); do_l<0>(rv, kvec, ldsrow); }
  else             { do_l<6>(rv, kvec, ldsrow); do_l<5>(rv, kvec, ldsrow); do_l<1>(rv, kvec, ldsrow); }
  __syncthreads();
  // flush: 6400 floats = 6.25 wave-rounds of float4. e = it*1024 + tid*4 (contiguous
  // per wave -> fully coalesced global stores). LDS word w = row*102 + col tracked
  // incrementally: e += 1024 -> row += 10, col += 24 (one carry max).
  unsigned e0 = (unsigned)tid * 4u;
  int row = (int)(e0 / 100u);              // magic-div once
  int col = (int)e0 - row * 100;
  int wi  = row * LSTRIDE + col;
  float* gout = out + (size_t)n0 * KMODES + e0;
#pragma unroll
  for (int it = 0; it < 6; ++it) {
    float2 lo = *reinterpret_cast<const float2*>(&lds[wi]);
    float2 hi = *reinterpret_cast<const float2*>(&lds[wi + 2]);
    *reinterpret_cast<float4*>(gout + it * 1024) = make_float4(lo.x, lo.y, hi.x, hi.y);
    col += 24; wi += 1044;                 // 10 rows + 24 cols
    if (col >= 100) { col -= 100; wi += 2; }
  }
  if (tid < 64) {                          // tail: e = 6144 + tid*4 < 6400
    float2 lo = *reinterpret_cast<const float2*>(&lds[wi]);
    float2 hi = *reinterpret_cast<const float2*>(&lds[wi + 2]);
    *reinterpret_cast<float4*>(gout + 6 * 1024) = make_float4(lo.x, lo.y, hi.x, hi.y);
  }
}

extern "C" void kernel_launch(void* const* d_in, const int* in_sizes, int n_in,
                              void* d_out, int out_size, void* d_ws, size_t ws_size,
                              hipStream_t stream) {
  const float* r = (const float*)d_in[0];
  const float* k = (const float*)d_in[1];
  float* out = (float*)d_out;
  int N = in_sizes[0];                   // 262144
  int blocks = N / NTILE;                // 4096
  sbf_kernel<<<blocks, 256, 0, stream>>>(r, k, out);
}